// Round 11
// baseline (146.514 us; speedup 1.0000x reference)
//
#include <hip/hip_runtime.h>
#include <stdint.h>

typedef __attribute__((ext_vector_type(8))) short short8;
typedef __attribute__((ext_vector_type(4))) short short4v;
typedef __attribute__((ext_vector_type(4))) float float4v;
typedef __attribute__((ext_vector_type(16))) float float16v;
typedef __attribute__((ext_vector_type(4))) uint32_t uint4v;

__device__ __forceinline__ short f2bf(float f) {
    union { float f; uint32_t u; } v; v.f = f;
    uint32_t u = v.u;
    uint32_t r = (u + 0x7fffu + ((u >> 16) & 1u)) >> 16;
    return (short)r;
}

// packed 2x fp32 -> 2x bf16 in one dword (low = first arg)
#if __has_builtin(__builtin_amdgcn_cvt_pk_bf16_f32)
typedef __bf16 bf16x2_t __attribute__((ext_vector_type(2)));
__device__ __forceinline__ uint32_t cvt_pk2(float a, float b) {
    union { bf16x2_t v; uint32_t u; } c;
    c.v = __builtin_amdgcn_cvt_pk_bf16_f32(a, b);
    return c.u;
}
#else
__device__ __forceinline__ uint32_t cvt_pk2(float a, float b) {
    union { float f; uint32_t u; } x, y; x.f = a; y.f = b;
    return ((x.u + 0x8000u) >> 16) | ((y.u + 0x8000u) & 0xFFFF0000u);
}
#endif

// ---------------- merged weight transpose-convert + ones buffer ----------------

__global__ __launch_bounds__(256) void cvtW_kernel(const float* __restrict__ wqkv,
                                                   const float* __restrict__ wproj,
                                                   short* __restrict__ outq,
                                                   short* __restrict__ outp,
                                                   short* __restrict__ ones) {
    int idx = blockIdx.x * 256 + threadIdx.x;
    if (idx < 196608) {
        int n = idx >> 8, k = idx & 255;
        outq[idx] = f2bf(wqkv[k * 768 + n]);
    } else if (idx < 262144) {
        int i = idx - 196608;
        int n = i >> 8, k = i & 255;
        outp[i] = f2bf(wproj[k * 256 + n]);
    } else {
        int i = idx - 262144;
        if (i < 2048) ones[i] = (short)0x3F80;  // bf16 1.0
    }
}

// ---------------- GEMM: C = A(Mx256) * Bt(Nx256)^T + bias ----------------
// NT n-tiles of 64 per block (A staged once per k-chunk, reused across tiles).
// MODE 0 (NT=2): A fp32 (x), bf16-converted during LDS staging; Q/K in
//   (B,H,N,D); V PRE-PERMUTED as VtG[bh][d][slot], slot = swap23(n) — the PV
//   A-operand layout. Q scaled log2(e).
// MODE 1 (NT=1): A bf16; fp32 out.

template<int MODE, int NT>
__global__ __launch_bounds__(256) void gemm_kernel(
    const void* __restrict__ Ap, const short* __restrict__ Bt,
    const float* __restrict__ bias,
    short* __restrict__ outQ, short* __restrict__ outK, short* __restrict__ outV,
    float* __restrict__ outP)
{
    const int K = 256;
    int m0 = blockIdx.x * 64;
    int n0 = blockIdx.y * (64 * NT);
    int tid = threadIdx.x;
    int wave = tid >> 6, lane = tid & 63, quad = lane >> 4, lc = lane & 15;

    __shared__ __align__(16) short As[64 * 48];
    __shared__ __align__(16) short Bs[NT][64 * 48];

    float4v acc[NT][4];
    #pragma unroll
    for (int nt = 0; nt < NT; ++nt)
        #pragma unroll
        for (int t = 0; t < 4; ++t) acc[nt][t] = (float4v){0.f, 0.f, 0.f, 0.f};

    int srow = tid >> 2, sseg = tid & 3;

    for (int c = 0; c < K; c += 32) {
        __syncthreads();
        if (MODE == 0) {
            const float* src = (const float*)Ap + (size_t)(m0 + srow) * K + c + sseg * 8;
            float4 f0 = *(const float4*)src;
            float4 f1 = *(const float4*)(src + 4);
            uint4v u; u.x = cvt_pk2(f0.x, f0.y); u.y = cvt_pk2(f0.z, f0.w);
            u.z = cvt_pk2(f1.x, f1.y); u.w = cvt_pk2(f1.z, f1.w);
            *(uint4v*)(&As[srow * 48 + sseg * 8]) = u;
        } else {
            *(short8*)(&As[srow * 48 + sseg * 8]) =
                *(const short8*)((const short*)Ap + (size_t)(m0 + srow) * K + c + sseg * 8);
        }
        #pragma unroll
        for (int nt = 0; nt < NT; ++nt)
            *(short8*)(&Bs[nt][srow * 48 + sseg * 8]) =
                *(const short8*)(Bt + (size_t)(n0 + nt * 64 + srow) * K + c + sseg * 8);
        __syncthreads();

        short8 af = *(short8*)(&As[(wave * 16 + lc) * 48 + quad * 8]);
        #pragma unroll
        for (int nt = 0; nt < NT; ++nt)
            #pragma unroll
            for (int t = 0; t < 4; ++t) {
                short8 bf = *(short8*)(&Bs[nt][(t * 16 + lc) * 48 + quad * 8]);
                acc[nt][t] = __builtin_amdgcn_mfma_f32_16x16x32_bf16(af, bf, acc[nt][t], 0, 0, 0);
            }
    }

    #pragma unroll
    for (int nt = 0; nt < NT; ++nt)
    #pragma unroll
    for (int t = 0; t < 4; ++t) {
        int cg = n0 + nt * 64 + t * 16 + lc;
        float bv = bias[cg];
        #pragma unroll
        for (int r = 0; r < 4; ++r) {
            int rg = m0 + wave * 16 + quad * 4 + r;
            float val = acc[nt][t][r] + bv;
            if (MODE == 0) {
                int sq = cg >> 8, rem = cg & 255, h = rem >> 4, d = rem & 15;
                int b = rg >> 11, n = rg & 2047;
                int bh = b * 16 + h;
                if (sq == 0) {
                    val *= 1.4426950408889634f;  // fold log2(e) into Q
                    outQ[((((size_t)bh) * 2048 + n) << 4) + d] = f2bf(val);
                } else if (sq == 1) {
                    outK[((((size_t)bh) * 2048 + n) << 4) + d] = f2bf(val);
                } else {
                    int sl = (n & ~12) | ((n & 4) << 1) | ((n & 8) >> 1);  // swap23
                    outV[((size_t)bh * 16 + d) * 2048 + sl] = f2bf(val);
                }
            } else {
                outP[(size_t)rg * 256 + cg] = val;
            }
        }
    }
}

// ---------------- flash attention: LDS-free, barrier-free, dual PV chains ----
// grid: (N/128, B*H), 256 threads (4 waves); wave w owns q rows qbase+w*32..+32.
// S^T = K*Q^T (32x32x16, C-layout col=q); exp2 in-regs; packed C regs are the
// B-operand of O^T = [V^T;1;...]*P^T.  V^T arrives PRE-PERMUTED in global
// memory (VtG[bh][d][slot], slot = swap23(n)); lanes m>=16 read a shared ones
// buffer (L falls out of MFMA D-row 16; rows 17..31 unread).
// NEW (r11): PV accumulates into TWO independent chains Oa/Ob (summed in the
// epilogue) — halves the serial MFMA-latency chain per iteration.

__global__ __launch_bounds__(256) void attn_kernel(
    const short* __restrict__ Q, const short* __restrict__ Kp,
    const short* __restrict__ Vt, const short* __restrict__ onesrow,
    short* __restrict__ Out)
{
    const int N = 2048;
    int bh = blockIdx.y;
    int b = bh >> 4, h = bh & 15;
    int tid = threadIdx.x;
    int wave = tid >> 6, lane = tid & 63;
    int m = lane & 31, hi = lane >> 5;
    int qbase = blockIdx.x * 128 + wave * 32;

    const short* Qh = Q + (size_t)bh * N * 16;
    const short* Kh = Kp + (size_t)bh * N * 16;
    const short* vbase = (m < 16) ? (Vt + ((size_t)bh * 16 + m) * 2048) : onesrow;

    short8 qf = *(const short8*)(Qh + (size_t)(qbase + m) * 16 + hi * 8);

    float16v Oa, Ob, zf;
    #pragma unroll
    for (int j = 0; j < 16; ++j) { Oa[j] = 0.f; Ob[j] = 0.f; zf[j] = 0.f; }

    // kf prefetch (c = 0)
    short8 kf1 = *(const short8*)(Kh + (size_t)m * 16 + hi * 8);
    short8 kf2 = *(const short8*)(Kh + (size_t)(32 + m) * 16 + hi * 8);

    #pragma unroll 4
    for (int c = 0; c < N; c += 64) {
        float16v S1 = __builtin_amdgcn_mfma_f32_32x32x16_bf16(kf1, qf, zf, 0, 0, 0);
        float16v S2 = __builtin_amdgcn_mfma_f32_32x32x16_bf16(kf2, qf, zf, 0, 0, 0);

        // prefetch next iteration's K fragments (wraps harmlessly at the end)
        int cn = (c + 64) & (N - 1);
        kf1 = *(const short8*)(Kh + (size_t)(cn + m) * 16 + hi * 8);
        kf2 = *(const short8*)(Kh + (size_t)(cn + 32 + m) * 16 + hi * 8);

        // V fragments — independent of S, latency hidden by the exp phase
        short8 vfr[4];
        #pragma unroll
        for (int p = 0; p < 4; ++p)
            vfr[p] = *(const short8*)(vbase + c + p * 16 + hi * 8);

        union { uint4v u; short8 s; } pA, pB, pC, pD;
        pA.u = (uint4v){
            cvt_pk2(__builtin_amdgcn_exp2f(S1[0]), __builtin_amdgcn_exp2f(S1[1])),
            cvt_pk2(__builtin_amdgcn_exp2f(S1[2]), __builtin_amdgcn_exp2f(S1[3])),
            cvt_pk2(__builtin_amdgcn_exp2f(S1[4]), __builtin_amdgcn_exp2f(S1[5])),
            cvt_pk2(__builtin_amdgcn_exp2f(S1[6]), __builtin_amdgcn_exp2f(S1[7]))};
        pB.u = (uint4v){
            cvt_pk2(__builtin_amdgcn_exp2f(S1[8]),  __builtin_amdgcn_exp2f(S1[9])),
            cvt_pk2(__builtin_amdgcn_exp2f(S1[10]), __builtin_amdgcn_exp2f(S1[11])),
            cvt_pk2(__builtin_amdgcn_exp2f(S1[12]), __builtin_amdgcn_exp2f(S1[13])),
            cvt_pk2(__builtin_amdgcn_exp2f(S1[14]), __builtin_amdgcn_exp2f(S1[15]))};
        pC.u = (uint4v){
            cvt_pk2(__builtin_amdgcn_exp2f(S2[0]), __builtin_amdgcn_exp2f(S2[1])),
            cvt_pk2(__builtin_amdgcn_exp2f(S2[2]), __builtin_amdgcn_exp2f(S2[3])),
            cvt_pk2(__builtin_amdgcn_exp2f(S2[4]), __builtin_amdgcn_exp2f(S2[5])),
            cvt_pk2(__builtin_amdgcn_exp2f(S2[6]), __builtin_amdgcn_exp2f(S2[7]))};
        pD.u = (uint4v){
            cvt_pk2(__builtin_amdgcn_exp2f(S2[8]),  __builtin_amdgcn_exp2f(S2[9])),
            cvt_pk2(__builtin_amdgcn_exp2f(S2[10]), __builtin_amdgcn_exp2f(S2[11])),
            cvt_pk2(__builtin_amdgcn_exp2f(S2[12]), __builtin_amdgcn_exp2f(S2[13])),
            cvt_pk2(__builtin_amdgcn_exp2f(S2[14]), __builtin_amdgcn_exp2f(S2[15]))};

        Oa = __builtin_amdgcn_mfma_f32_32x32x16_bf16(vfr[0], pA.s, Oa, 0, 0, 0);
        Ob = __builtin_amdgcn_mfma_f32_32x32x16_bf16(vfr[1], pB.s, Ob, 0, 0, 0);
        Oa = __builtin_amdgcn_mfma_f32_32x32x16_bf16(vfr[2], pC.s, Oa, 0, 0, 0);
        Ob = __builtin_amdgcn_mfma_f32_32x32x16_bf16(vfr[3], pD.s, Ob, 0, 0, 0);
    }

    // epilogue: merge chains; L = D-row 16 (reg 8, hi==0); O[q][d] = O_d / L
    float O0 = Oa[0] + Ob[0], O1 = Oa[1] + Ob[1], O2 = Oa[2] + Ob[2], O3 = Oa[3] + Ob[3];
    float O4 = Oa[4] + Ob[4], O5 = Oa[5] + Ob[5], O6 = Oa[6] + Ob[6], O7 = Oa[7] + Ob[7];
    float L8 = Oa[8] + Ob[8];
    float Lq = __shfl(L8, m, 64);
    float inv = 1.0f / Lq;
    uint32_t o0 = cvt_pk2(O0 * inv, O1 * inv);
    uint32_t o1 = cvt_pk2(O2 * inv, O3 * inv);
    uint32_t o2 = cvt_pk2(O4 * inv, O5 * inv);
    uint32_t o3 = cvt_pk2(O6 * inv, O7 * inv);
    short* row = Out + ((size_t)(b * 2048 + qbase + m)) * 256 + h * 16;
    uint2 w0; w0.x = o0; w0.y = o1;
    uint2 w1; w1.x = o2; w1.y = o3;
    *(uint2*)(row + hi * 4) = w0;
    *(uint2*)(row + 8 + hi * 4) = w1;
}

// ---------------- launcher ----------------

extern "C" void kernel_launch(void* const* d_in, const int* in_sizes, int n_in,
                              void* d_out, int out_size, void* d_ws, size_t ws_size,
                              hipStream_t stream) {
    const float* x      = (const float*)d_in[0];
    const float* w_qkv  = (const float*)d_in[1];
    const float* b_qkv  = (const float*)d_in[2];
    const float* w_proj = (const float*)d_in[3];
    const float* b_proj = (const float*)d_in[4];
    float* out = (float*)d_out;

    short* wqkvT  = (short*)d_ws;          // 768*256
    short* wprojT = wqkvT + 196608;        // 256*256
    short* Qb     = wprojT + 65536;        // (B*H, N, D) bf16
    short* Kb     = Qb + 2097152;
    short* VtG    = Kb + 2097152;          // (B*H, D, N-slots) bf16, pre-permuted
    short* Ab     = VtG + 2097152;         // attention output (B,N,C) bf16
    short* onesb  = Ab + 2097152;          // 2048 x bf16 1.0

    cvtW_kernel<<<1040, 256, 0, stream>>>(w_qkv, w_proj, wqkvT, wprojT, onesb);

    gemm_kernel<0, 2><<<dim3(128, 6), 256, 0, stream>>>(x, wqkvT, b_qkv, Qb, Kb, VtG, nullptr);

    attn_kernel<<<dim3(16, 64), 256, 0, stream>>>(Qb, Kb, VtG, onesb, Ab);

    gemm_kernel<1, 1><<<dim3(128, 4), 256, 0, stream>>>(Ab, wprojT, b_proj,
                                                        nullptr, nullptr, nullptr, out);
}

// Round 12
// 143.349 us; speedup vs baseline: 1.0221x; 1.0221x over previous
//
#include <hip/hip_runtime.h>
#include <stdint.h>

typedef __attribute__((ext_vector_type(8))) short short8;
typedef __attribute__((ext_vector_type(4))) short short4v;
typedef __attribute__((ext_vector_type(4))) float float4v;
typedef __attribute__((ext_vector_type(16))) float float16v;
typedef __attribute__((ext_vector_type(4))) uint32_t uint4v;

__device__ __forceinline__ short f2bf(float f) {
    union { float f; uint32_t u; } v; v.f = f;
    uint32_t u = v.u;
    uint32_t r = (u + 0x7fffu + ((u >> 16) & 1u)) >> 16;
    return (short)r;
}

// packed 2x fp32 -> 2x bf16 in one dword (low = first arg)
#if __has_builtin(__builtin_amdgcn_cvt_pk_bf16_f32)
typedef __bf16 bf16x2_t __attribute__((ext_vector_type(2)));
__device__ __forceinline__ uint32_t cvt_pk2(float a, float b) {
    union { bf16x2_t v; uint32_t u; } c;
    c.v = __builtin_amdgcn_cvt_pk_bf16_f32(a, b);
    return c.u;
}
#else
__device__ __forceinline__ uint32_t cvt_pk2(float a, float b) {
    union { float f; uint32_t u; } x, y; x.f = a; y.f = b;
    return ((x.u + 0x8000u) >> 16) | ((y.u + 0x8000u) & 0xFFFF0000u);
}
#endif

// ---------------- GEMM: C = A(Mx256) * W(256xN)[:, n0..n0+64] + bias --------
// B is taken DIRECTLY from the fp32 weight matrix W (k-major, row stride WN):
// staging reads 64-float k-rows coalesced, packs (k,k+1) pairs via cvt_pk2,
// and writes transposed bf16 to LDS (2k x 4n micro-tile per thread, aligned
// ds_write_b32).  This removes the separate cvtW transpose kernel entirely.
// MODE 0: A fp32 (x), bf16-converted during staging; outputs Q/K/V (B,H,N,D),
//         Q pre-scaled by log2(e).  WN=768.
// MODE 1: A bf16; fp32 out + bias.  WN=256.

template<int MODE>
__global__ __launch_bounds__(256) void gemm_kernel(
    const void* __restrict__ Ap, const float* __restrict__ W, int WN,
    const float* __restrict__ bias,
    short* __restrict__ outQ, short* __restrict__ outK, short* __restrict__ outV,
    float* __restrict__ outP)
{
    const int K = 256;
    int m0 = blockIdx.x * 64;
    int n0 = blockIdx.y * 64;
    int tid = threadIdx.x;
    int wave = tid >> 6, lane = tid & 63, quad = lane >> 4, lc = lane & 15;

    __shared__ __align__(16) short As[64 * 48];
    __shared__ __align__(16) short Bs[64 * 48];

    float4v acc[4];
    #pragma unroll
    for (int t = 0; t < 4; ++t) acc[t] = (float4v){0.f, 0.f, 0.f, 0.f};

    int srow = tid >> 2, sseg = tid & 3;          // A staging assignment
    int kk = (tid & 15) * 2, gseg = tid >> 4;     // B transpose staging: 2k x 4n

    for (int c = 0; c < K; c += 32) {
        __syncthreads();
        if (MODE == 0) {
            const float* src = (const float*)Ap + (size_t)(m0 + srow) * K + c + sseg * 8;
            float4 f0 = *(const float4*)src;
            float4 f1 = *(const float4*)(src + 4);
            uint4v u; u.x = cvt_pk2(f0.x, f0.y); u.y = cvt_pk2(f0.z, f0.w);
            u.z = cvt_pk2(f1.x, f1.y); u.w = cvt_pk2(f1.z, f1.w);
            *(uint4v*)(&As[srow * 48 + sseg * 8]) = u;
        } else {
            *(short8*)(&As[srow * 48 + sseg * 8]) =
                *(const short8*)((const short*)Ap + (size_t)(m0 + srow) * K + c + sseg * 8);
        }
        {   // B: coalesced fp32 reads of two k-rows, transposed bf16 LDS writes
            const float* w0 = W + (size_t)(c + kk) * WN + n0 + gseg * 4;
            float4 r0 = *(const float4*)w0;
            float4 r1 = *(const float4*)(w0 + WN);
            const float* r0p = (const float*)&r0;
            const float* r1p = (const float*)&r1;
            #pragma unroll
            for (int j = 0; j < 4; ++j) {
                uint32_t pk = cvt_pk2(r0p[j], r1p[j]);   // low = k, high = k+1
                *(uint32_t*)(&Bs[(gseg * 4 + j) * 48 + kk]) = pk;
            }
        }
        __syncthreads();

        short8 af = *(short8*)(&As[(wave * 16 + lc) * 48 + quad * 8]);
        #pragma unroll
        for (int t = 0; t < 4; ++t) {
            short8 bf = *(short8*)(&Bs[(t * 16 + lc) * 48 + quad * 8]);
            acc[t] = __builtin_amdgcn_mfma_f32_16x16x32_bf16(af, bf, acc[t], 0, 0, 0);
        }
    }

    #pragma unroll
    for (int t = 0; t < 4; ++t) {
        int cg = n0 + t * 16 + lc;
        float bv = bias[cg];
        #pragma unroll
        for (int r = 0; r < 4; ++r) {
            int rg = m0 + wave * 16 + quad * 4 + r;
            float val = acc[t][r] + bv;
            if (MODE == 0) {
                int sq = cg >> 8, rem = cg & 255, h = rem >> 4, d = rem & 15;
                int b = rg >> 11, n = rg & 2047;
                if (sq == 0) val *= 1.4426950408889634f;  // fold log2(e) into Q
                short* dst = (sq == 0) ? outQ : ((sq == 1) ? outK : outV);
                dst[((((size_t)b * 16 + h) * 2048 + n) << 4) + d] = f2bf(val);
            } else {
                outP[(size_t)rg * 256 + cg] = val;
            }
        }
    }
}

// ---------------- flash attention (r9 structure — best measured, 58.8 us) ----
// grid: (N/128, B*H), 256 threads (4 waves); wave w owns q rows qbase+w*32..+32.
// S^T = K*Q^T (32x32x16, C-layout col=q); exp2 in-regs; packed C regs are the
// B-operand of O^T = [V^T;1;0]*P^T (slot->key bit-swap folded into Vt staging).
// Register ones/zeros select for rows >=16 (L = MFMA D-row 16).  Pipelined:
// kf prefetch distance 1; V-stage regs loaded across both barriers.

__global__ __launch_bounds__(256) void attn_kernel(
    const short* __restrict__ Q, const short* __restrict__ Kp, const short* __restrict__ V,
    short* __restrict__ Out)
{
    const int N = 2048;
    int bh = blockIdx.y;
    int b = bh >> 4, h = bh & 15;
    int tid = threadIdx.x;
    int wave = tid >> 6, lane = tid & 63;
    int m = lane & 31, hi = lane >> 5;
    int qbase = blockIdx.x * 128 + wave * 32;

    const short* Qh = Q + (size_t)bh * N * 16;
    const short* Kh = Kp + (size_t)bh * N * 16;
    const short* Vh = V + (size_t)bh * N * 16;

    __shared__ __align__(16) short Vt[16][264];

    short8 qf = *(const short8*)(Qh + (size_t)(qbase + m) * 16 + hi * 8);

    short8 ones, zeros;
    #pragma unroll
    for (int j = 0; j < 8; ++j) { ones[j] = (short)0x3F80; zeros[j] = 0; }

    float16v Oacc, zf;
    #pragma unroll
    for (int j = 0; j < 16; ++j) { Oacc[j] = 0.f; zf[j] = 0.f; }

    int sd = tid & 15, sa = tid >> 4;
    int kb = ((sa & 1) << 3) | (((sa >> 1) & 1) << 2) | ((sa >> 2) << 4);

    // ---- V staging prefetch (chunk 0) ----
    short4v vpack[4];
    #pragma unroll
    for (int cc = 0; cc < 4; ++cc) {
        const short* vp = Vh + (size_t)(cc * 64 + kb) * 16 + sd;
        vpack[cc].x = vp[0]; vpack[cc].y = vp[16];
        vpack[cc].z = vp[32]; vpack[cc].w = vp[48];
    }

    // ---- kf prefetch (it 0) ----
    short8 kf1 = *(const short8*)(Kh + (size_t)m * 16 + hi * 8);
    short8 kf2 = *(const short8*)(Kh + (size_t)(32 + m) * 16 + hi * 8);

    for (int sc = 0; sc < N; sc += 256) {
        __syncthreads();
        #pragma unroll
        for (int cc = 0; cc < 4; ++cc)
            *(short4v*)(&Vt[sd][cc * 64 + sa * 4]) = vpack[cc];
        if (sc + 256 < N) {   // V prefetch for next chunk — in flight across barrier
            #pragma unroll
            for (int cc = 0; cc < 4; ++cc) {
                const short* vp = Vh + (size_t)(sc + 256 + cc * 64 + kb) * 16 + sd;
                vpack[cc].x = vp[0]; vpack[cc].y = vp[16];
                vpack[cc].z = vp[32]; vpack[cc].w = vp[48];
            }
        }
        __syncthreads();

        #pragma unroll
        for (int it = 0; it < 4; ++it) {
            int c = sc + it * 64;
            int cn = (c + 64) & (N - 1);   // next-it key base (wraps harmlessly)

            float16v S1 = __builtin_amdgcn_mfma_f32_32x32x16_bf16(kf1, qf, zf, 0, 0, 0);
            float16v S2 = __builtin_amdgcn_mfma_f32_32x32x16_bf16(kf2, qf, zf, 0, 0, 0);

            // prefetch next it's K fragments; latency hidden by exp/pack/PV below
            kf1 = *(const short8*)(Kh + (size_t)(cn + m) * 16 + hi * 8);
            kf2 = *(const short8*)(Kh + (size_t)(cn + 32 + m) * 16 + hi * 8);

            union { uint4v u; short8 s; } pA, pB, pC, pD;
            pA.u = (uint4v){
                cvt_pk2(__builtin_amdgcn_exp2f(S1[0]), __builtin_amdgcn_exp2f(S1[1])),
                cvt_pk2(__builtin_amdgcn_exp2f(S1[2]), __builtin_amdgcn_exp2f(S1[3])),
                cvt_pk2(__builtin_amdgcn_exp2f(S1[4]), __builtin_amdgcn_exp2f(S1[5])),
                cvt_pk2(__builtin_amdgcn_exp2f(S1[6]), __builtin_amdgcn_exp2f(S1[7]))};
            pB.u = (uint4v){
                cvt_pk2(__builtin_amdgcn_exp2f(S1[8]),  __builtin_amdgcn_exp2f(S1[9])),
                cvt_pk2(__builtin_amdgcn_exp2f(S1[10]), __builtin_amdgcn_exp2f(S1[11])),
                cvt_pk2(__builtin_amdgcn_exp2f(S1[12]), __builtin_amdgcn_exp2f(S1[13])),
                cvt_pk2(__builtin_amdgcn_exp2f(S1[14]), __builtin_amdgcn_exp2f(S1[15]))};
            pC.u = (uint4v){
                cvt_pk2(__builtin_amdgcn_exp2f(S2[0]), __builtin_amdgcn_exp2f(S2[1])),
                cvt_pk2(__builtin_amdgcn_exp2f(S2[2]), __builtin_amdgcn_exp2f(S2[3])),
                cvt_pk2(__builtin_amdgcn_exp2f(S2[4]), __builtin_amdgcn_exp2f(S2[5])),
                cvt_pk2(__builtin_amdgcn_exp2f(S2[6]), __builtin_amdgcn_exp2f(S2[7]))};
            pD.u = (uint4v){
                cvt_pk2(__builtin_amdgcn_exp2f(S2[8]),  __builtin_amdgcn_exp2f(S2[9])),
                cvt_pk2(__builtin_amdgcn_exp2f(S2[10]), __builtin_amdgcn_exp2f(S2[11])),
                cvt_pk2(__builtin_amdgcn_exp2f(S2[12]), __builtin_amdgcn_exp2f(S2[13])),
                cvt_pk2(__builtin_amdgcn_exp2f(S2[14]), __builtin_amdgcn_exp2f(S2[15]))};

            #pragma unroll
            for (int p = 0; p < 4; ++p) {
                short8 vf;
                if (m < 16)      vf = *(const short8*)(&Vt[m][it * 64 + p * 16 + hi * 8]);
                else if (m == 16) vf = ones;
                else              vf = zeros;
                short8 pf = (p == 0) ? pA.s : (p == 1) ? pB.s : (p == 2) ? pC.s : pD.s;
                Oacc = __builtin_amdgcn_mfma_f32_32x32x16_bf16(vf, pf, Oacc, 0, 0, 0);
            }
        }
    }

    // epilogue: L = row 16 (reg 8, hi==0 lanes); O[q][d] = Oacc_d / L
    float Lq = __shfl(Oacc[8], m, 64);
    float inv = 1.0f / Lq;
    uint32_t o0 = cvt_pk2(Oacc[0] * inv, Oacc[1] * inv);
    uint32_t o1 = cvt_pk2(Oacc[2] * inv, Oacc[3] * inv);
    uint32_t o2 = cvt_pk2(Oacc[4] * inv, Oacc[5] * inv);
    uint32_t o3 = cvt_pk2(Oacc[6] * inv, Oacc[7] * inv);
    short* row = Out + ((size_t)(b * 2048 + qbase + m)) * 256 + h * 16;
    uint2 w0; w0.x = o0; w0.y = o1;
    uint2 w1; w1.x = o2; w1.y = o3;
    *(uint2*)(row + hi * 4) = w0;
    *(uint2*)(row + 8 + hi * 4) = w1;
}

// ---------------- launcher (3 dispatches) ----------------

extern "C" void kernel_launch(void* const* d_in, const int* in_sizes, int n_in,
                              void* d_out, int out_size, void* d_ws, size_t ws_size,
                              hipStream_t stream) {
    const float* x      = (const float*)d_in[0];
    const float* w_qkv  = (const float*)d_in[1];
    const float* b_qkv  = (const float*)d_in[2];
    const float* w_proj = (const float*)d_in[3];
    const float* b_proj = (const float*)d_in[4];
    float* out = (float*)d_out;

    short* Qb = (short*)d_ws;              // (B*H, N, D) bf16
    short* Kb = Qb + 2097152;
    short* Vb = Kb + 2097152;
    short* Ab = Vb + 2097152;              // attention output (B,N,C) bf16

    gemm_kernel<0><<<dim3(128, 12), 256, 0, stream>>>(x, w_qkv, 768, b_qkv,
                                                      Qb, Kb, Vb, nullptr);

    attn_kernel<<<dim3(16, 64), 256, 0, stream>>>(Qb, Kb, Vb, Ab);

    gemm_kernel<1><<<dim3(128, 4), 256, 0, stream>>>(Ab, w_proj, 256, b_proj,
                                                     nullptr, nullptr, nullptr, out);
}

// Round 13
// 133.537 us; speedup vs baseline: 1.0972x; 1.0735x over previous
//
#include <hip/hip_runtime.h>
#include <stdint.h>

typedef __attribute__((ext_vector_type(8))) short short8;
typedef __attribute__((ext_vector_type(4))) short short4v;
typedef __attribute__((ext_vector_type(4))) float float4v;
typedef __attribute__((ext_vector_type(16))) float float16v;
typedef __attribute__((ext_vector_type(4))) uint32_t uint4v;

__device__ __forceinline__ short f2bf(float f) {
    union { float f; uint32_t u; } v; v.f = f;
    uint32_t u = v.u;
    uint32_t r = (u + 0x7fffu + ((u >> 16) & 1u)) >> 16;
    return (short)r;
}

// packed 2x fp32 -> 2x bf16 in one dword (low = first arg)
#if __has_builtin(__builtin_amdgcn_cvt_pk_bf16_f32)
typedef __bf16 bf16x2_t __attribute__((ext_vector_type(2)));
__device__ __forceinline__ uint32_t cvt_pk2(float a, float b) {
    union { bf16x2_t v; uint32_t u; } c;
    c.v = __builtin_amdgcn_cvt_pk_bf16_f32(a, b);
    return c.u;
}
#else
__device__ __forceinline__ uint32_t cvt_pk2(float a, float b) {
    union { float f; uint32_t u; } x, y; x.f = a; y.f = b;
    return ((x.u + 0x8000u) >> 16) | ((y.u + 0x8000u) & 0xFFFF0000u);
}
#endif

// ---------------- merged weight transpose-convert ----------------
// Done ONCE as its own dispatch: r12 proved fusing this into the GEMM K-loop
// re-converts W per m-block (128x redundant) and costs ~9 us net.

__global__ __launch_bounds__(256) void cvtW_kernel(const float* __restrict__ wqkv,
                                                   const float* __restrict__ wproj,
                                                   short* __restrict__ outq,
                                                   short* __restrict__ outp) {
    int idx = blockIdx.x * 256 + threadIdx.x;
    if (idx < 196608) {
        int n = idx >> 8, k = idx & 255;
        outq[idx] = f2bf(wqkv[k * 768 + n]);
    } else {
        int i = idx - 196608;
        int n = i >> 8, k = i & 255;
        outp[i] = f2bf(wproj[k * 256 + n]);
    }
}

// ---------------- GEMM (r5 structure — best measured): 64x64 tile ----------------
// MODE 0: A fp32 (x), bf16-converted during LDS staging; outputs Q/K/V
//         (B,H,N,D), Q pre-scaled by log2(e).  MODE 1: A bf16; fp32 out.

template<int MODE>
__global__ __launch_bounds__(256) void gemm_kernel(
    const void* __restrict__ Ap, const short* __restrict__ Bt,
    const float* __restrict__ bias,
    short* __restrict__ outQ, short* __restrict__ outK, short* __restrict__ outV,
    float* __restrict__ outP)
{
    const int K = 256;
    int m0 = blockIdx.x * 64;
    int n0 = blockIdx.y * 64;
    int tid = threadIdx.x;
    int wave = tid >> 6, lane = tid & 63, quad = lane >> 4, lc = lane & 15;

    __shared__ __align__(16) short As[64 * 48];
    __shared__ __align__(16) short Bs[64 * 48];

    float4v acc[4];
    #pragma unroll
    for (int t = 0; t < 4; ++t) acc[t] = (float4v){0.f, 0.f, 0.f, 0.f};

    int srow = tid >> 2, sseg = tid & 3;

    for (int c = 0; c < K; c += 32) {
        __syncthreads();
        if (MODE == 0) {
            const float* src = (const float*)Ap + (size_t)(m0 + srow) * K + c + sseg * 8;
            float4 f0 = *(const float4*)src;
            float4 f1 = *(const float4*)(src + 4);
            uint4v u; u.x = cvt_pk2(f0.x, f0.y); u.y = cvt_pk2(f0.z, f0.w);
            u.z = cvt_pk2(f1.x, f1.y); u.w = cvt_pk2(f1.z, f1.w);
            *(uint4v*)(&As[srow * 48 + sseg * 8]) = u;
        } else {
            *(short8*)(&As[srow * 48 + sseg * 8]) =
                *(const short8*)((const short*)Ap + (size_t)(m0 + srow) * K + c + sseg * 8);
        }
        *(short8*)(&Bs[srow * 48 + sseg * 8]) =
            *(const short8*)(Bt + (size_t)(n0 + srow) * K + c + sseg * 8);
        __syncthreads();

        short8 af = *(short8*)(&As[(wave * 16 + lc) * 48 + quad * 8]);
        #pragma unroll
        for (int t = 0; t < 4; ++t) {
            short8 bf = *(short8*)(&Bs[(t * 16 + lc) * 48 + quad * 8]);
            acc[t] = __builtin_amdgcn_mfma_f32_16x16x32_bf16(af, bf, acc[t], 0, 0, 0);
        }
    }

    #pragma unroll
    for (int t = 0; t < 4; ++t) {
        int cg = n0 + t * 16 + lc;
        float bv = bias[cg];
        #pragma unroll
        for (int r = 0; r < 4; ++r) {
            int rg = m0 + wave * 16 + quad * 4 + r;
            float val = acc[t][r] + bv;
            if (MODE == 0) {
                int sq = cg >> 8, rem = cg & 255, h = rem >> 4, d = rem & 15;
                int b = rg >> 11, n = rg & 2047;
                if (sq == 0) val *= 1.4426950408889634f;  // fold log2(e) into Q
                short* dst = (sq == 0) ? outQ : ((sq == 1) ? outK : outV);
                dst[((((size_t)b * 16 + h) * 2048 + n) << 4) + d] = f2bf(val);
            } else {
                outP[(size_t)rg * 256 + cg] = val;
            }
        }
    }
}

// ---------------- flash attention (r9 structure — best measured) ----------------
// grid: (N/128, B*H), 256 threads (4 waves); wave w owns q rows qbase+w*32..+32.
// S^T = K*Q^T (32x32x16, C-layout col=q); exp2 in-regs; packed C regs are the
// B-operand of O^T = [V^T;1;0]*P^T (slot->key bit-swap folded into Vt staging).
// Register ones/zeros select for rows >=16 (L = MFMA D-row 16).  Pipelined:
// kf prefetch distance 1; V-stage regs loaded across both barriers.

__global__ __launch_bounds__(256) void attn_kernel(
    const short* __restrict__ Q, const short* __restrict__ Kp, const short* __restrict__ V,
    short* __restrict__ Out)
{
    const int N = 2048;
    int bh = blockIdx.y;
    int b = bh >> 4, h = bh & 15;
    int tid = threadIdx.x;
    int wave = tid >> 6, lane = tid & 63;
    int m = lane & 31, hi = lane >> 5;
    int qbase = blockIdx.x * 128 + wave * 32;

    const short* Qh = Q + (size_t)bh * N * 16;
    const short* Kh = Kp + (size_t)bh * N * 16;
    const short* Vh = V + (size_t)bh * N * 16;

    __shared__ __align__(16) short Vt[16][264];

    short8 qf = *(const short8*)(Qh + (size_t)(qbase + m) * 16 + hi * 8);

    short8 ones, zeros;
    #pragma unroll
    for (int j = 0; j < 8; ++j) { ones[j] = (short)0x3F80; zeros[j] = 0; }

    float16v Oacc, zf;
    #pragma unroll
    for (int j = 0; j < 16; ++j) { Oacc[j] = 0.f; zf[j] = 0.f; }

    int sd = tid & 15, sa = tid >> 4;
    int kb = ((sa & 1) << 3) | (((sa >> 1) & 1) << 2) | ((sa >> 2) << 4);

    // ---- V staging prefetch (chunk 0) ----
    short4v vpack[4];
    #pragma unroll
    for (int cc = 0; cc < 4; ++cc) {
        const short* vp = Vh + (size_t)(cc * 64 + kb) * 16 + sd;
        vpack[cc].x = vp[0]; vpack[cc].y = vp[16];
        vpack[cc].z = vp[32]; vpack[cc].w = vp[48];
    }

    // ---- kf prefetch (it 0) ----
    short8 kf1 = *(const short8*)(Kh + (size_t)m * 16 + hi * 8);
    short8 kf2 = *(const short8*)(Kh + (size_t)(32 + m) * 16 + hi * 8);

    for (int sc = 0; sc < N; sc += 256) {
        __syncthreads();
        #pragma unroll
        for (int cc = 0; cc < 4; ++cc)
            *(short4v*)(&Vt[sd][cc * 64 + sa * 4]) = vpack[cc];
        if (sc + 256 < N) {   // V prefetch for next chunk — in flight across barrier
            #pragma unroll
            for (int cc = 0; cc < 4; ++cc) {
                const short* vp = Vh + (size_t)(sc + 256 + cc * 64 + kb) * 16 + sd;
                vpack[cc].x = vp[0]; vpack[cc].y = vp[16];
                vpack[cc].z = vp[32]; vpack[cc].w = vp[48];
            }
        }
        __syncthreads();

        #pragma unroll
        for (int it = 0; it < 4; ++it) {
            int c = sc + it * 64;
            int cn = (c + 64) & (N - 1);   // next-it key base (wraps harmlessly)

            float16v S1 = __builtin_amdgcn_mfma_f32_32x32x16_bf16(kf1, qf, zf, 0, 0, 0);
            float16v S2 = __builtin_amdgcn_mfma_f32_32x32x16_bf16(kf2, qf, zf, 0, 0, 0);

            // prefetch next it's K fragments; latency hidden by exp/pack/PV below
            kf1 = *(const short8*)(Kh + (size_t)(cn + m) * 16 + hi * 8);
            kf2 = *(const short8*)(Kh + (size_t)(cn + 32 + m) * 16 + hi * 8);

            union { uint4v u; short8 s; } pA, pB, pC, pD;
            pA.u = (uint4v){
                cvt_pk2(__builtin_amdgcn_exp2f(S1[0]), __builtin_amdgcn_exp2f(S1[1])),
                cvt_pk2(__builtin_amdgcn_exp2f(S1[2]), __builtin_amdgcn_exp2f(S1[3])),
                cvt_pk2(__builtin_amdgcn_exp2f(S1[4]), __builtin_amdgcn_exp2f(S1[5])),
                cvt_pk2(__builtin_amdgcn_exp2f(S1[6]), __builtin_amdgcn_exp2f(S1[7]))};
            pB.u = (uint4v){
                cvt_pk2(__builtin_amdgcn_exp2f(S1[8]),  __builtin_amdgcn_exp2f(S1[9])),
                cvt_pk2(__builtin_amdgcn_exp2f(S1[10]), __builtin_amdgcn_exp2f(S1[11])),
                cvt_pk2(__builtin_amdgcn_exp2f(S1[12]), __builtin_amdgcn_exp2f(S1[13])),
                cvt_pk2(__builtin_amdgcn_exp2f(S1[14]), __builtin_amdgcn_exp2f(S1[15]))};
            pC.u = (uint4v){
                cvt_pk2(__builtin_amdgcn_exp2f(S2[0]), __builtin_amdgcn_exp2f(S2[1])),
                cvt_pk2(__builtin_amdgcn_exp2f(S2[2]), __builtin_amdgcn_exp2f(S2[3])),
                cvt_pk2(__builtin_amdgcn_exp2f(S2[4]), __builtin_amdgcn_exp2f(S2[5])),
                cvt_pk2(__builtin_amdgcn_exp2f(S2[6]), __builtin_amdgcn_exp2f(S2[7]))};
            pD.u = (uint4v){
                cvt_pk2(__builtin_amdgcn_exp2f(S2[8]),  __builtin_amdgcn_exp2f(S2[9])),
                cvt_pk2(__builtin_amdgcn_exp2f(S2[10]), __builtin_amdgcn_exp2f(S2[11])),
                cvt_pk2(__builtin_amdgcn_exp2f(S2[12]), __builtin_amdgcn_exp2f(S2[13])),
                cvt_pk2(__builtin_amdgcn_exp2f(S2[14]), __builtin_amdgcn_exp2f(S2[15]))};

            #pragma unroll
            for (int p = 0; p < 4; ++p) {
                short8 vf;
                if (m < 16)      vf = *(const short8*)(&Vt[m][it * 64 + p * 16 + hi * 8]);
                else if (m == 16) vf = ones;
                else              vf = zeros;
                short8 pf = (p == 0) ? pA.s : (p == 1) ? pB.s : (p == 2) ? pC.s : pD.s;
                Oacc = __builtin_amdgcn_mfma_f32_32x32x16_bf16(vf, pf, Oacc, 0, 0, 0);
            }
        }
    }

    // epilogue: L = row 16 (reg 8, hi==0 lanes); O[q][d] = Oacc_d / L
    float Lq = __shfl(Oacc[8], m, 64);
    float inv = 1.0f / Lq;
    uint32_t o0 = cvt_pk2(Oacc[0] * inv, Oacc[1] * inv);
    uint32_t o1 = cvt_pk2(Oacc[2] * inv, Oacc[3] * inv);
    uint32_t o2 = cvt_pk2(Oacc[4] * inv, Oacc[5] * inv);
    uint32_t o3 = cvt_pk2(Oacc[6] * inv, Oacc[7] * inv);
    short* row = Out + ((size_t)(b * 2048 + qbase + m)) * 256 + h * 16;
    uint2 w0; w0.x = o0; w0.y = o1;
    uint2 w1; w1.x = o2; w1.y = o3;
    *(uint2*)(row + hi * 4) = w0;
    *(uint2*)(row + 8 + hi * 4) = w1;
}

// ---------------- launcher ----------------

extern "C" void kernel_launch(void* const* d_in, const int* in_sizes, int n_in,
                              void* d_out, int out_size, void* d_ws, size_t ws_size,
                              hipStream_t stream) {
    const float* x      = (const float*)d_in[0];
    const float* w_qkv  = (const float*)d_in[1];
    const float* b_qkv  = (const float*)d_in[2];
    const float* w_proj = (const float*)d_in[3];
    const float* b_proj = (const float*)d_in[4];
    float* out = (float*)d_out;

    short* wqkvT  = (short*)d_ws;          // 768*256
    short* wprojT = wqkvT + 196608;        // 256*256
    short* Qb     = wprojT + 65536;        // (B*H, N, D) bf16
    short* Kb     = Qb + 2097152;
    short* Vb     = Kb + 2097152;
    short* Ab     = Vb + 2097152;          // attention output (B,N,C) bf16

    cvtW_kernel<<<1024, 256, 0, stream>>>(w_qkv, w_proj, wqkvT, wprojT);

    gemm_kernel<0><<<dim3(128, 12), 256, 0, stream>>>(x, wqkvT, b_qkv, Qb, Kb, Vb, nullptr);

    attn_kernel<<<dim3(16, 64), 256, 0, stream>>>(Qb, Kb, Vb, Ab);

    gemm_kernel<1><<<dim3(128, 4), 256, 0, stream>>>(Ab, wprojT, b_proj,
                                                     nullptr, nullptr, nullptr, out);
}